// Round 1
// baseline (847.697 us; speedup 1.0000x reference)
//
#include <hip/hip_runtime.h>

typedef __attribute__((ext_vector_type(8))) short short8;
typedef __attribute__((ext_vector_type(4))) float f32x4;

#define BATCH   131072
#define IND     300
#define MIDD    450
#define XS      328   // LDS row stride (bf16 elems) for K=300->320 buffers; 656B = 41*16B, 2-way bank alias only
#define HS      488   // LDS row stride for K=450->480 buffers; 976B = 61*16B, 2-way alias
#define BM      64
#define NTHR    512

constexpr int SZ1 = 464 * XS;     // padded [464][328] for N=450,K=300 weights
constexpr int SZ2 = 304 * HS;     // padded [304][488] for N=300,K=450 weights
constexpr int O_NOT1 = 0;
constexpr int O_NOT2 = SZ1;
constexpr int O_AND1 = SZ1 + SZ2;
constexpr int O_AND2 = 2 * SZ1 + SZ2;
constexpr int O_OR1  = 2 * SZ1 + 2 * SZ2;
constexpr int O_OR2  = 3 * SZ1 + 2 * SZ2;
constexpr int WS_ELEMS = 3 * SZ1 + 3 * SZ2;          // ~902K bf16 = 1.8 MB
constexpr int LDS_BYTES = BM * (XS + HS + XS) * 2;   // 146432 B

__device__ __forceinline__ unsigned short f2b(float f) {
  unsigned u = __builtin_bit_cast(unsigned, f);
  u = (u + 0x7FFFu + ((u >> 16) & 1u)) >> 16;   // RNE
  return (unsigned short)u;
}
__device__ __forceinline__ float b2f(unsigned short h) {
  unsigned u = ((unsigned)h) << 16;
  return __builtin_bit_cast(float, u);
}

__device__ __forceinline__ f32x4 mfma16(short8 a, short8 b, f32x4 c) {
  asm("v_mfma_f32_16x16x32_bf16 %0, %1, %2, %0" : "+v"(c) : "v"(a), "v"(b));
  return c;
}

// ---- weight prep: f32 -> bf16, zero-padded; AND/OR first layers folded over the concat ----
__global__ void prep_weights(const float* __restrict__ nw1, const float* __restrict__ nw2,
                             const float* __restrict__ aw1, const float* __restrict__ aw2,
                             const float* __restrict__ ow1, const float* __restrict__ ow2,
                             unsigned short* __restrict__ ws)
{
  int idx = blockIdx.x * 256 + threadIdx.x;
  if (idx < 3 * SZ1) {
    int r = idx / SZ1, off = idx % SZ1;
    int n = off / XS, k = off % XS;
    float v = 0.f;
    if (n < MIDD && k < IND) {
      if (r == 0) v = nw1[n * IND + k];
      else {
        const float* s = (r == 1) ? aw1 : ow1;
        v = s[n * 2 * IND + k] + s[n * 2 * IND + IND + k];   // fold concat([x,x]) halves
      }
    }
    int base = (r == 0) ? O_NOT1 : (r == 1) ? O_AND1 : O_OR1;
    ws[base + off] = f2b(v);
  } else if (idx < WS_ELEMS) {
    int i2 = idx - 3 * SZ1;
    int r = i2 / SZ2, off = i2 % SZ2;
    int n = off / HS, k = off % HS;
    float v = 0.f;
    if (n < IND && k < MIDD) {
      const float* s = (r == 0) ? nw2 : (r == 1) ? aw2 : ow2;
      v = s[n * MIDD + k];
    }
    int base = (r == 0) ? O_NOT2 : (r == 1) ? O_AND2 : O_OR2;
    ws[base + off] = f2b(v);
  }
}

// ---- one GEMM stage: OUT[BM][N] = leaky(IN[BM][K] @ W^T + b); or fused MSE vs X ----
// Fragment layouts (16x16x32 bf16): A lane: m=l&15, k=8*(l>>4)+i (contiguous 8)
//                                   B lane: n=l&15, k=8*(l>>4)+i  -> W row-major [n][k] is exactly B
//                                   D lane: n=l&15, m=(l>>4)*4+r  (m89-verified)
template <int KB, int N, bool MSE>
__device__ __forceinline__ void stage(const unsigned short* __restrict__ IN, int in_stride,
                                      const unsigned short* __restrict__ W, int w_stride,
                                      const float* __restrict__ bias,
                                      unsigned short* __restrict__ OUT, int out_stride,
                                      const unsigned short* __restrict__ XB,
                                      float& sq, int wid, int l16, int lhi)
{
  constexpr int NT = (N + 15) / 16;
  constexpr int NJ = (NT + 7) / 8;
  f32x4 acc[4][NJ];
#pragma unroll
  for (int m = 0; m < 4; m++)
#pragma unroll
    for (int j = 0; j < NJ; j++) acc[m][j] = f32x4{0.f, 0.f, 0.f, 0.f};

  for (int kb = 0; kb < KB; kb++) {
    int kcol = kb * 32 + lhi * 8;
    short8 a[4];
#pragma unroll
    for (int m = 0; m < 4; m++)
      a[m] = *(const short8*)&IN[(m * 16 + l16) * in_stride + kcol];
#pragma unroll
    for (int j = 0; j < NJ; j++) {
      int nt = wid + 8 * j;
      if (nt < NT) {
        short8 b = *(const short8*)&W[(nt * 16 + l16) * w_stride + kcol];
#pragma unroll
        for (int m = 0; m < 4; m++)
          acc[m][j] = mfma16(a[m], b, acc[m][j]);
      }
    }
  }

#pragma unroll
  for (int j = 0; j < NJ; j++) {
    int nt = wid + 8 * j;
    if (nt >= NT) continue;
    int col = nt * 16 + l16;
    bool valid = col < N;
    float bv = valid ? bias[col] : 0.f;
#pragma unroll
    for (int m = 0; m < 4; m++) {
#pragma unroll
      for (int r = 0; r < 4; r++) {
        int row = m * 16 + lhi * 4 + r;
        float v = acc[m][j][r] + bv;
        v = v > 0.f ? v : 0.1f * v;
        if (MSE) {
          if (valid) { float d = b2f(XB[row * XS + col]) - v; sq += d * d; }
        } else {
          if (valid) OUT[row * out_stride + col] = f2b(v);
        }
      }
    }
  }
}

__global__ __launch_bounds__(NTHR, 2)
void fused(const float* __restrict__ x, const unsigned short* __restrict__ ws,
           const float* __restrict__ nb1, const float* __restrict__ nb2,
           const float* __restrict__ ab1, const float* __restrict__ ab2,
           const float* __restrict__ ob1, const float* __restrict__ ob2,
           float* __restrict__ out)
{
  extern __shared__ unsigned short lds[];
  unsigned short* X  = lds;                         // [64][XS] x tile (bf16), persists
  unsigned short* P0 = lds + BM * XS;               // [64][HS] mid activations
  unsigned short* P1 = lds + BM * (XS + HS);        // [64][XS] s1
  int tid = threadIdx.x, wid = tid >> 6, lane = tid & 63;
  int l16 = lane & 15, lhi = lane >> 4;

  // zero all LDS (K-pad columns must be 0 so padded MFMA K-blocks contribute 0)
  int nu32 = (BM * (XS + HS + XS)) >> 1;
  for (int i = tid; i < nu32; i += NTHR) ((unsigned*)lds)[i] = 0u;
  __syncthreads();

  int row0 = blockIdx.x * BM;
  for (int i = tid; i < BM * IND; i += NTHR) {
    int r = i / IND, c = i - r * IND;
    X[r * XS + c] = f2b(x[(row0 + r) * IND + c]);
  }
  __syncthreads();

  float sq = 0.f;
  // NOT(NOT(x)) path
  stage<10, MIDD, false>(X,  XS, ws + O_NOT1, XS, nb1, P0, HS, nullptr, sq, wid, l16, lhi);
  __syncthreads();
  stage<15, IND,  false>(P0, HS, ws + O_NOT2, HS, nb2, P1, XS, nullptr, sq, wid, l16, lhi);
  __syncthreads();
  stage<10, MIDD, false>(P1, XS, ws + O_NOT1, XS, nb1, P0, HS, nullptr, sq, wid, l16, lhi);
  __syncthreads();
  stage<15, IND,  true >(P0, HS, ws + O_NOT2, HS, nb2, nullptr, 0, X, sq, wid, l16, lhi);
  __syncthreads();
  // AND path (folded W1)
  stage<10, MIDD, false>(X,  XS, ws + O_AND1, XS, ab1, P0, HS, nullptr, sq, wid, l16, lhi);
  __syncthreads();
  stage<15, IND,  true >(P0, HS, ws + O_AND2, HS, ab2, nullptr, 0, X, sq, wid, l16, lhi);
  __syncthreads();
  // OR path (folded W1)
  stage<10, MIDD, false>(X,  XS, ws + O_OR1,  XS, ob1, P0, HS, nullptr, sq, wid, l16, lhi);
  __syncthreads();
  stage<15, IND,  true >(P0, HS, ws + O_OR2,  HS, ob2, nullptr, 0, X, sq, wid, l16, lhi);

  // block reduction -> atomicAdd
#pragma unroll
  for (int off = 32; off > 0; off >>= 1) sq += __shfl_down(sq, off);
  __shared__ float wsum[8];
  if (lane == 0) wsum[wid] = sq;
  __syncthreads();
  if (tid == 0) {
    float s = 0.f;
#pragma unroll
    for (int w = 0; w < 8; w++) s += wsum[w];
    atomicAdd(out, s);
  }
}

__global__ void finalize(float* out) {
  out[0] *= (1.0f / (3.0f * (float)BATCH * (float)IND));
}

extern "C" void kernel_launch(void* const* d_in, const int* in_sizes, int n_in,
                              void* d_out, int out_size, void* d_ws, size_t ws_size,
                              hipStream_t stream) {
  const float* x   = (const float*)d_in[0];
  const float* nw1 = (const float*)d_in[1];
  const float* nb1 = (const float*)d_in[2];
  const float* nw2 = (const float*)d_in[3];
  const float* nb2 = (const float*)d_in[4];
  const float* aw1 = (const float*)d_in[5];
  const float* ab1 = (const float*)d_in[6];
  const float* aw2 = (const float*)d_in[7];
  const float* ab2 = (const float*)d_in[8];
  const float* ow1 = (const float*)d_in[9];
  const float* ob1 = (const float*)d_in[10];
  const float* ow2 = (const float*)d_in[11];
  const float* ob2 = (const float*)d_in[12];
  unsigned short* ws = (unsigned short*)d_ws;
  float* out = (float*)d_out;

  hipMemsetAsync(d_out, 0, sizeof(float), stream);

  int prep_blocks = (WS_ELEMS + 255) / 256;
  prep_weights<<<prep_blocks, 256, 0, stream>>>(nw1, nw2, aw1, aw2, ow1, ow2, ws);

  hipFuncSetAttribute((const void*)fused,
                      hipFuncAttributeMaxDynamicSharedMemorySize, LDS_BYTES);
  fused<<<BATCH / BM, NTHR, LDS_BYTES, stream>>>(x, ws, nb1, nb2, ab1, ab2, ob1, ob2, out);

  finalize<<<1, 1, 0, stream>>>(out);
}

// Round 2
// 779.360 us; speedup vs baseline: 1.0877x; 1.0877x over previous
//
#include <hip/hip_runtime.h>

typedef __attribute__((ext_vector_type(8))) short short8;
typedef __attribute__((ext_vector_type(4))) float f32x4;

#define BATCH   131072
#define IND     300
#define MIDD    450
#define XS      328   // X row stride (elems); 656B = 41*16, bank step 4 -> 2-way (free)
#define HS      488   // H row stride (elems); 976B = 61*16, bank step 20 -> 2-way (free)
#define BM      64
#define NTHR    512

constexpr int SZ1 = 464 * XS;     // [464][328] padded N450,K320 weights
constexpr int SZ2 = 304 * HS;     // [304][488] padded N300,K480 weights
constexpr int O_NOT1 = 0;
constexpr int O_NOT2 = SZ1;
constexpr int O_AND1 = SZ1 + SZ2;
constexpr int O_AND2 = 2 * SZ1 + SZ2;
constexpr int O_OR1  = 2 * SZ1 + 2 * SZ2;
constexpr int O_OR2  = 3 * SZ1 + 2 * SZ2;
constexpr int WS_ELEMS = 3 * SZ1 + 3 * SZ2;

constexpr int XBYTES = BM * XS * 2;           // 41984
constexpr int HBYTES = BM * HS * 2;           // 62464
constexpr int SLICE_BYTES = 464 * 64;         // 29696 (max K32-slice: 464 rows x 64B)
constexpr int LDS_BYTES = XBYTES + HBYTES + 2 * SLICE_BYTES;  // 163840 = 160 KiB exactly

__device__ __forceinline__ unsigned short f2b(float f) {
  unsigned u = __builtin_bit_cast(unsigned, f);
  u = (u + 0x7FFFu + ((u >> 16) & 1u)) >> 16;   // RNE
  return (unsigned short)u;
}
__device__ __forceinline__ float b2f(unsigned short h) {
  unsigned u = ((unsigned)h) << 16;
  return __builtin_bit_cast(float, u);
}
__device__ __forceinline__ f32x4 mfma16(short8 a, short8 b, f32x4 c) {
  asm("v_mfma_f32_16x16x32_bf16 %0, %1, %2, %0" : "+v"(c) : "v"(a), "v"(b));
  return c;
}

// ---- weight prep: f32 -> bf16, zero-padded; AND/OR first layers folded over concat ----
__global__ void prep_weights(const float* __restrict__ nw1, const float* __restrict__ nw2,
                             const float* __restrict__ aw1, const float* __restrict__ aw2,
                             const float* __restrict__ ow1, const float* __restrict__ ow2,
                             unsigned short* __restrict__ ws)
{
  int idx = blockIdx.x * 256 + threadIdx.x;
  if (idx < 3 * SZ1) {
    int r = idx / SZ1, off = idx % SZ1;
    int n = off / XS, k = off % XS;
    float v = 0.f;
    if (n < MIDD && k < IND) {
      if (r == 0) v = nw1[n * IND + k];
      else {
        const float* s = (r == 1) ? aw1 : ow1;
        v = s[n * 2 * IND + k] + s[n * 2 * IND + IND + k];   // fold concat([x,x])
      }
    }
    int base = (r == 0) ? O_NOT1 : (r == 1) ? O_AND1 : O_OR1;
    ws[base + off] = f2b(v);
  } else if (idx < WS_ELEMS) {
    int i2 = idx - 3 * SZ1;
    int r = i2 / SZ2, off = i2 % SZ2;
    int n = off / HS, k = off % HS;
    float v = 0.f;
    if (n < IND && k < MIDD) {
      const float* s = (r == 0) ? nw2 : (r == 1) ? aw2 : ow2;
      v = s[n * MIDD + k];
    }
    int base = (r == 0) ? O_NOT2 : (r == 1) ? O_AND2 : O_OR2;
    ws[base + off] = f2b(v);
  }
}

// ---- stage one K=32 weight slice into LDS via global_load_lds(16B) ----
// LDS layout: [WROWS][64B] with XOR swizzle byte ^= ((row&7)<<4), achieved by
// permuting the per-lane GLOBAL source (m173 pattern: linear dest, swizzled src).
template <int WROWS>
__device__ __forceinline__ void stage_W(const unsigned short* __restrict__ Wg,
                                        int wg_stride, int k0, char* wbuf, int tid)
{
  constexpr int CHUNKS = WROWS * 4;               // 16B chunks
  constexpr int ITER = (CHUNKS + NTHR - 1) / NTHR;
#pragma unroll
  for (int i = 0; i < ITER; i++) {
    int c = i * NTHR + tid;
    if (c < CHUNKS) {
      int n = c >> 2;
      int bs = ((c & 3) << 4) ^ ((n & 7) << 4);   // swizzled byte-in-row
      const unsigned short* src = Wg + n * wg_stride + k0 + (bs >> 1);
      __builtin_amdgcn_global_load_lds((const __attribute__((address_space(1))) void*)src,
                                       (__attribute__((address_space(3))) void*)(wbuf + c * 16),
                                       16, 0, 0);
    }
  }
}

// ---- one GEMM stage: OUT[64][N] = leaky(IN[64][K] @ W^T + b); MSE variant fuses vs X ----
// 16x16x32 bf16 frags: A lane: m=l&15,k=8*(l>>4)+i ; B lane: n=l&15,k=8*(l>>4)+i
// D lane: n=l&15, m=(l>>4)*4+r  (m89-verified; validated in round 1)
template <int KB, int NT, int N, bool MSE>
__device__ __forceinline__ void stage(const unsigned short* __restrict__ IN, int in_stride,
                                      const unsigned short* __restrict__ Wg, int wg_stride,
                                      const float* __restrict__ bias,
                                      unsigned short* __restrict__ Hout,
                                      const unsigned short* __restrict__ XT,
                                      char* __restrict__ wbuf,
                                      float& sq, int tid, int wn, int l16, int lhi)
{
  constexpr int NJ = (NT + 7) / 8;
  constexpr int WROWS = NT * 16;
  f32x4 acc[4][NJ];
#pragma unroll
  for (int m = 0; m < 4; m++)
#pragma unroll
    for (int j = 0; j < NJ; j++) acc[m][j] = f32x4{0.f, 0.f, 0.f, 0.f};

  const unsigned short* rowp[4];
#pragma unroll
  for (int m = 0; m < 4; m++) rowp[m] = IN + (m * 16 + l16) * in_stride + lhi * 8;
  int boff[NJ];
#pragma unroll
  for (int j = 0; j < NJ; j++) {
    int row = (wn + 8 * j) * 16 + l16;
    boff[j] = row * 64 + ((lhi * 16) ^ ((row & 7) << 4));
  }

  stage_W<WROWS>(Wg, wg_stride, 0, wbuf, tid);
  __syncthreads();                       // slice 0 resident (barrier drains vmcnt)
  char* wb_rd = wbuf;
  char* wb_wr = wbuf + SLICE_BYTES;
#pragma unroll 1
  for (int kb = 0; kb < KB; kb++) {
    if (kb + 1 < KB) stage_W<WROWS>(Wg, wg_stride, (kb + 1) * 32, wb_wr, tid);  // prefetch
    short8 a[4];
#pragma unroll
    for (int m = 0; m < 4; m++) a[m] = *(const short8*)(rowp[m] + kb * 32);
#pragma unroll
    for (int j = 0; j < NJ; j++) {
      if (wn + 8 * j < NT) {            // wave-uniform guard
        short8 b = *(const short8*)(wb_rd + boff[j]);
#pragma unroll
        for (int m = 0; m < 4; m++) acc[m][j] = mfma16(a[m], b, acc[m][j]);
      }
    }
    __syncthreads();                     // next slice ready + wb_rd free for reuse
    char* t = wb_rd; wb_rd = wb_wr; wb_wr = t;
  }

  // epilogue (after final barrier -> in-place H overwrite is safe)
#pragma unroll
  for (int j = 0; j < NJ; j++) {
    int nt = wn + 8 * j;
    if (nt >= NT) continue;
    int col = nt * 16 + l16;
    bool valid = col < N;
    float bv = valid ? bias[col] : 0.f;
#pragma unroll
    for (int m = 0; m < 4; m++) {
#pragma unroll
      for (int r = 0; r < 4; r++) {
        int row = m * 16 + lhi * 4 + r;
        float v = acc[m][j][r] + bv;
        v = v > 0.f ? v : 0.1f * v;
        if (MSE) {
          if (valid) { float d = b2f(XT[row * XS + col]) - v; sq += d * d; }
        } else {
          if (valid) Hout[row * HS + col] = f2b(v);
        }
      }
    }
  }
  if (!MSE && N == IND) {
    // zero pad cols [300,320) so the next K=320 read sees zeros
    for (int i = tid; i < BM * 20; i += NTHR) {
      int r = i / 20, c = i - r * 20;
      Hout[r * HS + IND + c] = 0;
    }
  }
}

__global__ __launch_bounds__(NTHR, 2)
void fused(const float* __restrict__ x, const unsigned short* __restrict__ ws,
           const float* __restrict__ nb1, const float* __restrict__ nb2,
           const float* __restrict__ ab1, const float* __restrict__ ab2,
           const float* __restrict__ ob1, const float* __restrict__ ob2,
           float* __restrict__ out)
{
  extern __shared__ __align__(16) char smem[];
  unsigned short* X = (unsigned short*)smem;                 // [64][XS]
  unsigned short* H = (unsigned short*)(smem + XBYTES);      // [64][HS]
  char* wbuf = smem + XBYTES + HBYTES;                       // 2 x SLICE_BYTES
  int tid = threadIdx.x, wid = tid >> 6, lane = tid & 63;
  int l16 = lane & 15, lhi = lane >> 4;

  // zero X+H (pads must be 0)
  for (int i = tid; i < (XBYTES + HBYTES) / 4; i += NTHR) ((unsigned*)smem)[i] = 0u;
  __syncthreads();

  int row0 = blockIdx.x * BM;
  for (int i = tid; i < BM * IND; i += NTHR) {
    int r = i / IND, c = i - r * IND;
    X[r * XS + c] = f2b(x[(row0 + r) * IND + c]);
  }
  __syncthreads();

  float sq = 0.f;
  // NOT(NOT(x))
  stage<10, 29, MIDD, false>(X, XS, ws + O_NOT1, XS, nb1, H, X, wbuf, sq, tid, wid, l16, lhi);
  stage<15, 19, IND,  false>(H, HS, ws + O_NOT2, HS, nb2, H, X, wbuf, sq, tid, wid, l16, lhi);
  stage<10, 29, MIDD, false>(H, HS, ws + O_NOT1, XS, nb1, H, X, wbuf, sq, tid, wid, l16, lhi);
  stage<15, 19, IND,  true >(H, HS, ws + O_NOT2, HS, nb2, H, X, wbuf, sq, tid, wid, l16, lhi);
  // AND (folded W1)
  stage<10, 29, MIDD, false>(X, XS, ws + O_AND1, XS, ab1, H, X, wbuf, sq, tid, wid, l16, lhi);
  stage<15, 19, IND,  true >(H, HS, ws + O_AND2, HS, ab2, H, X, wbuf, sq, tid, wid, l16, lhi);
  // OR (folded W1)
  stage<10, 29, MIDD, false>(X, XS, ws + O_OR1,  XS, ob1, H, X, wbuf, sq, tid, wid, l16, lhi);
  stage<15, 19, IND,  true >(H, HS, ws + O_OR2,  HS, ob2, H, X, wbuf, sq, tid, wid, l16, lhi);

#pragma unroll
  for (int off = 32; off > 0; off >>= 1) sq += __shfl_down(sq, off);
  float* wsum = (float*)wbuf;           // W buffer is free now
  if (lane == 0) wsum[wid] = sq;
  __syncthreads();
  if (tid == 0) {
    float s = 0.f;
#pragma unroll
    for (int w = 0; w < 8; w++) s += wsum[w];
    atomicAdd(out, s);
  }
}

__global__ void finalize(float* out) {
  out[0] *= (1.0f / (3.0f * (float)BATCH * (float)IND));
}

extern "C" void kernel_launch(void* const* d_in, const int* in_sizes, int n_in,
                              void* d_out, int out_size, void* d_ws, size_t ws_size,
                              hipStream_t stream) {
  const float* x   = (const float*)d_in[0];
  const float* nw1 = (const float*)d_in[1];
  const float* nb1 = (const float*)d_in[2];
  const float* nw2 = (const float*)d_in[3];
  const float* nb2 = (const float*)d_in[4];
  const float* aw1 = (const float*)d_in[5];
  const float* ab1 = (const float*)d_in[6];
  const float* aw2 = (const float*)d_in[7];
  const float* ab2 = (const float*)d_in[8];
  const float* ow1 = (const float*)d_in[9];
  const float* ob1 = (const float*)d_in[10];
  const float* ow2 = (const float*)d_in[11];
  const float* ob2 = (const float*)d_in[12];
  unsigned short* ws = (unsigned short*)d_ws;
  float* out = (float*)d_out;

  hipMemsetAsync(d_out, 0, sizeof(float), stream);

  int prep_blocks = (WS_ELEMS + 255) / 256;
  prep_weights<<<prep_blocks, 256, 0, stream>>>(nw1, nw2, aw1, aw2, ow1, ow2, ws);

  hipFuncSetAttribute((const void*)fused,
                      hipFuncAttributeMaxDynamicSharedMemorySize, LDS_BYTES);
  fused<<<BATCH / BM, NTHR, LDS_BYTES, stream>>>(x, ws, nb1, nb2, ab1, ab2, ob1, ob2, out);

  finalize<<<1, 1, 0, stream>>>(out);
}

// Round 3
// 620.848 us; speedup vs baseline: 1.3654x; 1.2553x over previous
//
#include <hip/hip_runtime.h>

typedef __attribute__((ext_vector_type(8))) short short8;
typedef __attribute__((ext_vector_type(4))) float f32x4;

#define BATCH   131072
#define IND     300
#define MIDD    450
#define XS      328   // X row stride (elems); 656B: bank step 4 -> 2-way alias (free)
#define HS      488   // H row stride (elems); 976B: bank step 20 -> 2-way alias (free)
#define BM      64
#define NTHR    512

constexpr int SZ1 = 464 * XS;     // [464][328] padded N450,K320 weights (row-major, bf16)
constexpr int SZ2 = 304 * HS;     // [304][488] padded N300,K480 weights
constexpr int O_NOT1 = 0;
constexpr int O_NOT2 = SZ1;
constexpr int O_AND1 = SZ1 + SZ2;
constexpr int O_AND2 = 2 * SZ1 + SZ2;
constexpr int O_OR1  = 2 * SZ1 + 2 * SZ2;
constexpr int O_OR2  = 3 * SZ1 + 2 * SZ2;
constexpr int WS_ELEMS = 3 * SZ1 + 3 * SZ2;

constexpr int XBYTES = BM * XS * 2;           // 41984
constexpr int HBYTES = BM * HS * 2;           // 62464
constexpr int LDS_BYTES = XBYTES + HBYTES;    // 104448

__device__ __forceinline__ unsigned short f2b(float f) {
  unsigned u = __builtin_bit_cast(unsigned, f);
  u = (u + 0x7FFFu + ((u >> 16) & 1u)) >> 16;   // RNE
  return (unsigned short)u;
}
__device__ __forceinline__ float b2f(unsigned short h) {
  unsigned u = ((unsigned)h) << 16;
  return __builtin_bit_cast(float, u);
}
__device__ __forceinline__ f32x4 mfma16(short8 a, short8 b, f32x4 c) {
  asm("v_mfma_f32_16x16x32_bf16 %0, %1, %2, %0" : "+v"(c) : "v"(a), "v"(b));
  return c;
}

// ---- weight prep: f32 -> bf16, zero-padded; AND/OR first layers folded over concat ----
__global__ void prep_weights(const float* __restrict__ nw1, const float* __restrict__ nw2,
                             const float* __restrict__ aw1, const float* __restrict__ aw2,
                             const float* __restrict__ ow1, const float* __restrict__ ow2,
                             unsigned short* __restrict__ ws)
{
  int idx = blockIdx.x * 256 + threadIdx.x;
  if (idx < 3 * SZ1) {
    int r = idx / SZ1, off = idx % SZ1;
    int n = off / XS, k = off % XS;
    float v = 0.f;
    if (n < MIDD && k < IND) {
      if (r == 0) v = nw1[n * IND + k];
      else {
        const float* s = (r == 1) ? aw1 : ow1;
        v = s[n * 2 * IND + k] + s[n * 2 * IND + IND + k];   // fold concat([x,x])
      }
    }
    int base = (r == 0) ? O_NOT1 : (r == 1) ? O_AND1 : O_OR1;
    ws[base + off] = f2b(v);
  } else if (idx < WS_ELEMS) {
    int i2 = idx - 3 * SZ1;
    int r = i2 / SZ2, off = i2 % SZ2;
    int n = off / HS, k = off % HS;
    float v = 0.f;
    if (n < IND && k < MIDD) {
      const float* s = (r == 0) ? nw2 : (r == 1) ? aw2 : ow2;
      v = s[n * MIDD + k];
    }
    int base = (r == 0) ? O_NOT2 : (r == 1) ? O_AND2 : O_OR2;
    ws[base + off] = f2b(v);
  }
}

// ---- one GEMM stage: OUT[64][N] = leaky(IN[64][K] @ W^T + b); MSE variant fuses vs X ----
// A from LDS (ds_read_b128), B from L2 via register depth-2 pipeline. No K-step barriers.
// 16x16x32 bf16 frags: A lane: m=l&15,k=8*(l>>4)+i ; B lane: n=l&15,k=8*(l>>4)+i
// D lane: n=l&15, m=(l>>4)*4+r  (validated rounds 1-2)
template <int KB, int NT, int N, bool MSE>
__device__ __forceinline__ void stage(const unsigned short* __restrict__ IN, int in_stride,
                                      const unsigned short* __restrict__ Wg, int wg_stride,
                                      const float* __restrict__ bias,
                                      unsigned short* __restrict__ Hout,
                                      const unsigned short* __restrict__ XT,
                                      float& sq, int tid, int wn, int l16, int lhi)
{
  constexpr int NJ = (NT + 7) / 8;
  f32x4 acc[4][NJ];
#pragma unroll
  for (int m = 0; m < 4; m++)
#pragma unroll
    for (int j = 0; j < NJ; j++) acc[m][j] = f32x4{0.f, 0.f, 0.f, 0.f};

  const unsigned short* ap[4];
#pragma unroll
  for (int m = 0; m < 4; m++) ap[m] = IN + (m * 16 + l16) * in_stride + lhi * 8;
  const unsigned short* bp[NJ];
#pragma unroll
  for (int j = 0; j < NJ; j++) {
    int nt = wn + 8 * j;
    int row = (nt < NT ? nt : 0) * 16 + l16;      // clamp invalid tiles to row 0 (never loaded)
    bp[j] = Wg + row * wg_stride + lhi * 8;
  }

  short8 a0[4], a1[4], b0[NJ], b1[NJ], b2[NJ];

#define LA_(buf, kk)                                                     \
  { _Pragma("unroll") for (int m = 0; m < 4; m++)                        \
      buf[m] = *(const short8*)(ap[m] + (kk) * 32); }
#define LB_(buf, kk)                                                     \
  { _Pragma("unroll") for (int j = 0; j < NJ; j++)                       \
      if (wn + 8 * j < NT) buf[j] = *(const short8*)(bp[j] + (kk) * 32); }

  LB_(b0, 0);
  if (KB > 1) LB_(b1, 1);
  LA_(a0, 0);

#pragma unroll
  for (int kb = 0; kb < KB; kb++) {
    short8* ac = (kb & 1) ? a1 : a0;
    short8* an = (kb & 1) ? a0 : a1;
    short8* bc = (kb % 3 == 0) ? b0 : (kb % 3 == 1) ? b1 : b2;
    short8* bn = ((kb + 2) % 3 == 0) ? b0 : ((kb + 2) % 3 == 1) ? b1 : b2;
    if (kb + 2 < KB) LB_(bn, kb + 2);     // depth-2 global prefetch (counted vmcnt)
    if (kb + 1 < KB) LA_(an, kb + 1);     // depth-1 LDS prefetch
#pragma unroll
    for (int j = 0; j < NJ; j++) {
      if (wn + 8 * j < NT) {
#pragma unroll
        for (int m = 0; m < 4; m++) acc[m][j] = mfma16(ac[m], bc[j], acc[m][j]);
      }
    }
  }
#undef LA_
#undef LB_

  if (!MSE) __syncthreads();   // in-place H overwrite: all waves done reading IN

#pragma unroll
  for (int j = 0; j < NJ; j++) {
    int nt = wn + 8 * j;
    if (nt >= NT) continue;
    int col = nt * 16 + l16;
    bool valid = col < N;
    float bv = valid ? bias[col] : 0.f;
#pragma unroll
    for (int m = 0; m < 4; m++) {
#pragma unroll
      for (int r = 0; r < 4; r++) {
        int row = m * 16 + lhi * 4 + r;
        float v = acc[m][j][r] + bv;
        v = v > 0.f ? v : 0.1f * v;
        if (MSE) {
          if (valid) { float d = b2f(XT[row * XS + col]) - v; sq += d * d; }
        } else {
          if (valid) Hout[row * HS + col] = f2b(v);
        }
      }
    }
  }
  if (!MSE && N == IND) {
    // zero pad cols [300,320) so the next K=320 read sees zeros
    for (int i = tid; i < BM * 20; i += NTHR) {
      int r = i / 20, c = i - r * 20;
      Hout[r * HS + IND + c] = 0;
    }
  }
}

__global__ __launch_bounds__(NTHR, 2)
void fused(const float* __restrict__ x, const unsigned short* __restrict__ ws,
           const float* __restrict__ nb1, const float* __restrict__ nb2,
           const float* __restrict__ ab1, const float* __restrict__ ab2,
           const float* __restrict__ ob1, const float* __restrict__ ob2,
           float* __restrict__ out)
{
  extern __shared__ __align__(16) char smem[];
  unsigned short* X = (unsigned short*)smem;                 // [64][XS]
  unsigned short* H = (unsigned short*)(smem + XBYTES);      // [64][HS]
  int tid = threadIdx.x, wid = tid >> 6, lane = tid & 63;
  int l16 = lane & 15, lhi = lane >> 4;

  // zero X+H (K-pad columns must be 0)
  for (int i = tid; i < LDS_BYTES / 4; i += NTHR) ((unsigned*)smem)[i] = 0u;
  __syncthreads();

  int row0 = blockIdx.x * BM;
  for (int i = tid; i < BM * IND; i += NTHR) {
    int r = i / IND, c = i - r * IND;
    X[r * XS + c] = f2b(x[(row0 + r) * IND + c]);
  }
  __syncthreads();

  float sq = 0.f;
  // NOT(NOT(x))
  stage<10, 29, MIDD, false>(X, XS, ws + O_NOT1, XS, nb1, H, X, sq, tid, wid, l16, lhi);
  __syncthreads();
  stage<15, 19, IND,  false>(H, HS, ws + O_NOT2, HS, nb2, H, X, sq, tid, wid, l16, lhi);
  __syncthreads();
  stage<10, 29, MIDD, false>(H, HS, ws + O_NOT1, XS, nb1, H, X, sq, tid, wid, l16, lhi);
  __syncthreads();
  stage<15, 19, IND,  true >(H, HS, ws + O_NOT2, HS, nb2, H, X, sq, tid, wid, l16, lhi);
  __syncthreads();
  // AND (folded W1)
  stage<10, 29, MIDD, false>(X, XS, ws + O_AND1, XS, ab1, H, X, sq, tid, wid, l16, lhi);
  __syncthreads();
  stage<15, 19, IND,  true >(H, HS, ws + O_AND2, HS, ab2, H, X, sq, tid, wid, l16, lhi);
  __syncthreads();
  // OR (folded W1)
  stage<10, 29, MIDD, false>(X, XS, ws + O_OR1,  XS, ob1, H, X, sq, tid, wid, l16, lhi);
  __syncthreads();
  stage<15, 19, IND,  true >(H, HS, ws + O_OR2,  HS, ob2, H, X, sq, tid, wid, l16, lhi);

#pragma unroll
  for (int off = 32; off > 0; off >>= 1) sq += __shfl_down(sq, off);
  __shared__ float wsum[8];
  if (lane == 0) wsum[wid] = sq;
  __syncthreads();
  if (tid == 0) {
    float s = 0.f;
#pragma unroll
    for (int w = 0; w < 8; w++) s += wsum[w];
    atomicAdd(out, s);
  }
}

__global__ void finalize(float* out) {
  out[0] *= (1.0f / (3.0f * (float)BATCH * (float)IND));
}

extern "C" void kernel_launch(void* const* d_in, const int* in_sizes, int n_in,
                              void* d_out, int out_size, void* d_ws, size_t ws_size,
                              hipStream_t stream) {
  const float* x   = (const float*)d_in[0];
  const float* nw1 = (const float*)d_in[1];
  const float* nb1 = (const float*)d_in[2];
  const float* nw2 = (const float*)d_in[3];
  const float* nb2 = (const float*)d_in[4];
  const float* aw1 = (const float*)d_in[5];
  const float* ab1 = (const float*)d_in[6];
  const float* aw2 = (const float*)d_in[7];
  const float* ab2 = (const float*)d_in[8];
  const float* ow1 = (const float*)d_in[9];
  const float* ob1 = (const float*)d_in[10];
  const float* ow2 = (const float*)d_in[11];
  const float* ob2 = (const float*)d_in[12];
  unsigned short* ws = (unsigned short*)d_ws;
  float* out = (float*)d_out;

  hipMemsetAsync(d_out, 0, sizeof(float), stream);

  int prep_blocks = (WS_ELEMS + 255) / 256;
  prep_weights<<<prep_blocks, 256, 0, stream>>>(nw1, nw2, aw1, aw2, ow1, ow2, ws);

  hipFuncSetAttribute((const void*)fused,
                      hipFuncAttributeMaxDynamicSharedMemorySize, LDS_BYTES);
  fused<<<BATCH / BM, NTHR, LDS_BYTES, stream>>>(x, ws, nb1, nb2, ab1, ab2, ob1, ob2, out);

  finalize<<<1, 1, 0, stream>>>(out);
}